// Round 1
// baseline (1696.599 us; speedup 1.0000x reference)
//
#include <hip/hip_runtime.h>

#define N_NODES 50000
#define N_EDGES 800000
#define HID 128
#define DEPTH 10
#define N_GRAPHS 512
#define IN_F 32

#define TM 64                       // GEMM rows per block
#define NBLK ((N_NODES + TM - 1) / TM)   // 782
#define PADN (NBLK * TM)            // 50048 padded rows

// -------------------- embed: h = x @ W_embed --------------------
// 1000 blocks x 128 threads, 50 nodes per block. W (16KB) staged in LDS.
__global__ __launch_bounds__(128) void embed_kernel(
    const float* __restrict__ x, const float* __restrict__ W, float* __restrict__ h) {
    __shared__ float Ws[IN_F * HID];
    int t = threadIdx.x;
    for (int i = t; i < IN_F * HID; i += 128) Ws[i] = W[i];
    __syncthreads();
    int nbeg = blockIdx.x * 50;
    for (int n = nbeg; n < nbeg + 50; ++n) {
        float acc = 0.f;
#pragma unroll
        for (int k = 0; k < IN_F; ++k)
            acc += x[(size_t)n * IN_F + k] * Ws[k * HID + t];
        h[(size_t)n * HID + t] = acc;
    }
}

// -------------------- CSR build --------------------
__global__ __launch_bounds__(256) void hist_kernel(const int* __restrict__ idx, int* __restrict__ count, int n) {
    int e = blockIdx.x * 256 + threadIdx.x;
    if (e < n) atomicAdd(&count[idx[e]], 1);
}

// single-block exclusive scan of count[n] -> ptr[0..n], optional cursor copy
__global__ __launch_bounds__(1024) void scan_kernel(
    const int* __restrict__ count, int* __restrict__ ptr, int* __restrict__ cursor, int n) {
    __shared__ int sums[1024];
    int tid = threadIdx.x;
    int per = (n + 1023) / 1024;
    int start = tid * per;
    int end = min(start + per, n);
    int s = 0;
    for (int i = start; i < end; ++i) s += count[i];
    sums[tid] = s;
    __syncthreads();
    for (int off = 1; off < 1024; off <<= 1) {
        int v = 0;
        if (tid >= off) v = sums[tid - off];
        __syncthreads();
        if (tid >= off) sums[tid] += v;
        __syncthreads();
    }
    int run = (tid == 0) ? 0 : sums[tid - 1];
    for (int i = start; i < end; ++i) {
        ptr[i] = run;
        if (cursor) cursor[i] = run;
        run += count[i];
    }
    if (tid == 1023) ptr[n] = sums[1023];
}

__global__ __launch_bounds__(256) void scatter_kernel(
    const int* __restrict__ src, const int* __restrict__ dst,
    int* __restrict__ cursor, int* __restrict__ sorted_src) {
    int e = blockIdx.x * 256 + threadIdx.x;
    if (e < N_EDGES) {
        int p = atomicAdd(&cursor[dst[e]], 1);
        sorted_src[p] = src[e];
    }
}

// -------------------- aggregate: agg[n] = sum_{e in CSR[n]} h[src[e]] --------------------
__global__ __launch_bounds__(128) void aggregate_kernel(
    const float* __restrict__ h, const int* __restrict__ row_ptr,
    const int* __restrict__ sorted_src, float* __restrict__ agg) {
    int n = blockIdx.x;
    int t = threadIdx.x;  // 128 = one feature per thread, 512B coalesced row reads
    int beg = row_ptr[n], end = row_ptr[n + 1];
    float acc = 0.f;
    int j = beg;
    // unroll-by-4 to pipeline the gather loads
    for (; j + 4 <= end; j += 4) {
        int s0 = sorted_src[j], s1 = sorted_src[j + 1], s2 = sorted_src[j + 2], s3 = sorted_src[j + 3];
        float v0 = h[(size_t)s0 * HID + t];
        float v1 = h[(size_t)s1 * HID + t];
        float v2 = h[(size_t)s2 * HID + t];
        float v3 = h[(size_t)s3 * HID + t];
        acc += v0 + v1 + v2 + v3;
    }
    for (; j < end; ++j) acc += h[(size_t)sorted_src[j] * HID + t];
    agg[(size_t)n * HID + t] = acc;
}

// -------------------- layer GEMM: hout = agg@Wrel + h@Wroot + bias --------------------
// Tile: 64 rows x 128 cols, 256 threads, 8x4 micro-tile/thread, K chunked by 16.
__global__ __launch_bounds__(256) void layer_gemm(
    const float* __restrict__ agg, const float* __restrict__ h,
    const float* __restrict__ Wrel, const float* __restrict__ Wroot,
    const float* __restrict__ bias, float* __restrict__ hout) {
    __shared__ float As[TM * 16];
    __shared__ float Bs[16 * HID];
    int tid = threadIdx.x;
    int m0 = blockIdx.x * TM;
    int cg = tid & 31;   // column group: 4 cols each
    int rg = tid >> 5;   // row group: 8 rows each
    int n0 = cg * 4;
    float acc[8][4] = {};

    for (int pass = 0; pass < 2; ++pass) {
        const float* A = pass ? h : agg;
        const float* B = pass ? Wroot : Wrel;
        for (int kc = 0; kc < HID; kc += 16) {
            __syncthreads();
            {   // A tile: 64x16 floats, each thread one float4
                int r = tid >> 2;
                int k4 = (tid & 3) * 4;
                *reinterpret_cast<float4*>(&As[r * 16 + k4]) =
                    *reinterpret_cast<const float4*>(&A[(size_t)(m0 + r) * HID + kc + k4]);
            }
            {   // B tile: 16x128 floats, each thread two float4
                int k = tid >> 5;
                int n = (tid & 31) * 4;
                *reinterpret_cast<float4*>(&Bs[k * HID + n]) =
                    *reinterpret_cast<const float4*>(&B[(size_t)(kc + k) * HID + n]);
                *reinterpret_cast<float4*>(&Bs[(k + 8) * HID + n]) =
                    *reinterpret_cast<const float4*>(&B[(size_t)(kc + k + 8) * HID + n]);
            }
            __syncthreads();
#pragma unroll
            for (int kk = 0; kk < 16; ++kk) {
                float b0 = Bs[kk * HID + n0];
                float b1 = Bs[kk * HID + n0 + 1];
                float b2 = Bs[kk * HID + n0 + 2];
                float b3 = Bs[kk * HID + n0 + 3];
#pragma unroll
                for (int r = 0; r < 8; ++r) {
                    float a = As[(rg * 8 + r) * 16 + kk];
                    acc[r][0] += a * b0;
                    acc[r][1] += a * b1;
                    acc[r][2] += a * b2;
                    acc[r][3] += a * b3;
                }
            }
        }
    }

    float4 bv = *reinterpret_cast<const float4*>(&bias[n0]);
#pragma unroll
    for (int r = 0; r < 8; ++r) {
        int m = m0 + rg * 8 + r;
        float4 o;
        o.x = acc[r][0] + bv.x;
        o.y = acc[r][1] + bv.y;
        o.z = acc[r][2] + bv.z;
        o.w = acc[r][3] + bv.w;
        *reinterpret_cast<float4*>(&hout[(size_t)m * HID + n0]) = o;
    }
}

// -------------------- per-layer pooled accumulation --------------------
// batch_map is sorted -> graph g's nodes are [graph_ptr[g], graph_ptr[g+1])
__global__ __launch_bounds__(128) void pool_kernel(
    const float* __restrict__ h, const int* __restrict__ graph_ptr,
    float* __restrict__ pooled, int layer) {
    int g = blockIdx.x;
    int t = threadIdx.x;
    int beg = graph_ptr[g], end = graph_ptr[g + 1];
    float acc = 0.f;
    for (int i = beg; i < end; ++i) acc += h[(size_t)i * HID + t];
    pooled[(size_t)g * (DEPTH * HID) + layer * HID + t] = acc;
}

// -------------------- final: out = pooled @ W_sg + b_sg --------------------
__global__ __launch_bounds__(256) void final_kernel(
    const float* __restrict__ pooled, const float* __restrict__ Wsg,
    const float* __restrict__ bsg, float* __restrict__ out) {
    int t = threadIdx.x & 31;
    int g = blockIdx.x * 8 + (threadIdx.x >> 5);
    float acc = bsg[t];
    const float* prow = pooled + (size_t)g * (DEPTH * HID);
    for (int k = 0; k < DEPTH * HID; ++k)
        acc += prow[k] * Wsg[k * IN_F + t];
    out[g * IN_F + t] = acc;
}

extern "C" void kernel_launch(void* const* d_in, const int* in_sizes, int n_in,
                              void* d_out, int out_size, void* d_ws, size_t ws_size,
                              hipStream_t stream) {
    const float* x       = (const float*)d_in[0];
    const int*   edge    = (const int*)d_in[1];
    const int*   bmap    = (const int*)d_in[2];
    // d_in[3] = num_graphs (fixed 512), d_in[8]/d_in[9] = W_ws/b_ws (dead: softmax over dim-1 == 1)
    const float* W_embed = (const float*)d_in[4];
    const float* W_rel   = (const float*)d_in[5];
    const float* b_rel   = (const float*)d_in[6];
    const float* W_root  = (const float*)d_in[7];
    const float* W_sg    = (const float*)d_in[10];
    const float* b_sg    = (const float*)d_in[11];
    float* out = (float*)d_out;

    const int* src = edge;            // edge_index[0]
    const int* dst = edge + N_EDGES;  // edge_index[1]

    char* ws = (char*)d_ws;
    auto alloc = [&](size_t bytes) -> char* {
        char* p = ws;
        ws += (bytes + 255) & ~(size_t)255;
        return p;
    };
    float* h_a       = (float*)alloc((size_t)PADN * HID * 4);
    float* h_b       = (float*)alloc((size_t)PADN * HID * 4);
    float* agg       = (float*)alloc((size_t)PADN * HID * 4);
    float* pooled    = (float*)alloc((size_t)N_GRAPHS * DEPTH * HID * 4);
    int*   counts    = (int*)alloc((size_t)N_NODES * 4);
    int*   row_ptr   = (int*)alloc((size_t)(N_NODES + 1) * 4);
    int*   cursor    = (int*)alloc((size_t)N_NODES * 4);
    int*   sorted_src= (int*)alloc((size_t)N_EDGES * 4);
    int*   gcount    = (int*)alloc((size_t)N_GRAPHS * 4);
    int*   graph_ptr = (int*)alloc((size_t)(N_GRAPHS + 1) * 4);

    hipMemsetAsync(counts, 0, (size_t)N_NODES * 4, stream);
    hipMemsetAsync(gcount, 0, (size_t)N_GRAPHS * 4, stream);

    embed_kernel<<<1000, 128, 0, stream>>>(x, W_embed, h_a);

    hist_kernel<<<(N_EDGES + 255) / 256, 256, 0, stream>>>(dst, counts, N_EDGES);
    hist_kernel<<<(N_NODES + 255) / 256, 256, 0, stream>>>(bmap, gcount, N_NODES);
    scan_kernel<<<1, 1024, 0, stream>>>(counts, row_ptr, cursor, N_NODES);
    scan_kernel<<<1, 1024, 0, stream>>>(gcount, graph_ptr, nullptr, N_GRAPHS);
    scatter_kernel<<<(N_EDGES + 255) / 256, 256, 0, stream>>>(src, dst, cursor, sorted_src);

    float* hc = h_a;
    float* hn = h_b;
    for (int i = 0; i < DEPTH; ++i) {
        aggregate_kernel<<<N_NODES, 128, 0, stream>>>(hc, row_ptr, sorted_src, agg);
        layer_gemm<<<NBLK, 256, 0, stream>>>(agg, hc,
                                             W_rel + (size_t)i * HID * HID,
                                             W_root + (size_t)i * HID * HID,
                                             b_rel + (size_t)i * HID, hn);
        pool_kernel<<<N_GRAPHS, 128, 0, stream>>>(hn, graph_ptr, pooled, i);
        float* tmp = hc; hc = hn; hn = tmp;
    }

    final_kernel<<<N_GRAPHS / 8, 256, 0, stream>>>(pooled, W_sg, b_sg, out);
}

// Round 2
// 1319.853 us; speedup vs baseline: 1.2854x; 1.2854x over previous
//
#include <hip/hip_runtime.h>

#define N_NODES 50000
#define N_EDGES 800000
#define HID 128
#define DEPTH 10
#define N_GRAPHS 512
#define IN_F 32

#define TM 64                       // GEMM rows per block
#define NBLK ((N_NODES + TM - 1) / TM)   // 782
#define PADN (NBLK * TM)            // 50048 padded rows

#define SB 256                      // scan block size
#define NSB ((N_NODES + SB - 1) / SB)    // 196

// -------------------- embed: h = x @ W_embed --------------------
__global__ __launch_bounds__(128) void embed_kernel(
    const float* __restrict__ x, const float* __restrict__ W, float* __restrict__ h) {
    __shared__ float Ws[IN_F * HID];
    int t = threadIdx.x;
    for (int i = t; i < IN_F * HID; i += 128) Ws[i] = W[i];
    __syncthreads();
    int nbeg = blockIdx.x * 50;
    for (int n = nbeg; n < nbeg + 50; ++n) {
        float acc = 0.f;
#pragma unroll
        for (int k = 0; k < IN_F; ++k)
            acc += x[(size_t)n * IN_F + k] * Ws[k * HID + t];
        h[(size_t)n * HID + t] = acc;
    }
}

// -------------------- CSR build --------------------
__global__ __launch_bounds__(256) void hist_kernel(const int* __restrict__ idx, int* __restrict__ count, int n) {
    int e = blockIdx.x * 256 + threadIdx.x;
    if (e < n) atomicAdd(&count[idx[e]], 1);
}

// phase 1: per-block sums
__global__ __launch_bounds__(SB) void scan_part1(
    const int* __restrict__ count, int* __restrict__ bsum, int n) {
    __shared__ int s[SB];
    int t = threadIdx.x;
    int i = blockIdx.x * SB + t;
    s[t] = (i < n) ? count[i] : 0;
    __syncthreads();
    for (int off = SB / 2; off >= 1; off >>= 1) {
        if (t < off) s[t] += s[t + off];
        __syncthreads();
    }
    if (t == 0) bsum[blockIdx.x] = s[0];
}

// phase 2: single-block exclusive scan of block sums (nb <= 256)
__global__ __launch_bounds__(256) void scan_part2(
    const int* __restrict__ bsum, int* __restrict__ boff, int nb) {
    __shared__ int s[256];
    int t = threadIdx.x;
    int v0 = (t < nb) ? bsum[t] : 0;
    s[t] = v0;
    __syncthreads();
    for (int off = 1; off < 256; off <<= 1) {
        int v = (t >= off) ? s[t - off] : 0;
        __syncthreads();
        s[t] += v;
        __syncthreads();
    }
    boff[t] = (t == 0) ? 0 : s[t - 1];
}

// phase 3: local inclusive scan + block offset -> exclusive ptr (+cursor copy)
__global__ __launch_bounds__(SB) void scan_part3(
    const int* __restrict__ count, const int* __restrict__ boff,
    int* __restrict__ ptr, int* __restrict__ cursor, int n) {
    __shared__ int s[SB];
    int b = blockIdx.x, t = threadIdx.x;
    int i = b * SB + t;
    int v = (i < n) ? count[i] : 0;
    s[t] = v;
    __syncthreads();
    for (int off = 1; off < SB; off <<= 1) {
        int u = (t >= off) ? s[t - off] : 0;
        __syncthreads();
        s[t] += u;
        __syncthreads();
    }
    int excl = s[t] - v + boff[b];
    if (i < n) {
        ptr[i] = excl;
        cursor[i] = excl;
        if (i == n - 1) ptr[n] = excl + v;
    }
}

__global__ __launch_bounds__(256) void scatter_kernel(
    const int* __restrict__ src, const int* __restrict__ dst,
    int* __restrict__ cursor, int* __restrict__ sorted_src) {
    int e = blockIdx.x * 256 + threadIdx.x;
    if (e < N_EDGES) {
        int p = atomicAdd(&cursor[dst[e]], 1);
        sorted_src[p] = src[e];
    }
}

// -------------------- aggregate: agg[n] = sum_{e in CSR[n]} h[src[e]] --------------------
__global__ __launch_bounds__(128) void aggregate_kernel(
    const float* __restrict__ h, const int* __restrict__ row_ptr,
    const int* __restrict__ sorted_src, float* __restrict__ agg) {
    int n = blockIdx.x;
    int t = threadIdx.x;  // 128 = one feature per thread, 512B coalesced row reads
    int beg = row_ptr[n], end = row_ptr[n + 1];
    float acc = 0.f;
    int j = beg;
    for (; j + 4 <= end; j += 4) {
        int s0 = sorted_src[j], s1 = sorted_src[j + 1], s2 = sorted_src[j + 2], s3 = sorted_src[j + 3];
        float v0 = h[(size_t)s0 * HID + t];
        float v1 = h[(size_t)s1 * HID + t];
        float v2 = h[(size_t)s2 * HID + t];
        float v3 = h[(size_t)s3 * HID + t];
        acc += v0 + v1 + v2 + v3;
    }
    for (; j < end; ++j) acc += h[(size_t)sorted_src[j] * HID + t];
    agg[(size_t)n * HID + t] = acc;
}

// -------------------- layer GEMM: hout = agg@Wrel + h@Wroot + bias, fused pooling --------------------
// Tile: 64 rows x 128 cols, 256 threads, 8x4 micro-tile/thread, K chunked by 16.
// Epilogue: batch_map is sorted; each thread's 8 consecutive rows span ~1 graph ->
// run-length accumulate then atomicAdd per (graph, col) into pooled.
__global__ __launch_bounds__(256) void layer_gemm(
    const float* __restrict__ agg, const float* __restrict__ h,
    const float* __restrict__ Wrel, const float* __restrict__ Wroot,
    const float* __restrict__ bias, float* __restrict__ hout,
    const int* __restrict__ bmap, float* __restrict__ pooled, int layer) {
    __shared__ float As[TM * 16];
    __shared__ float Bs[16 * HID];
    int tid = threadIdx.x;
    int m0 = blockIdx.x * TM;
    int cg = tid & 31;   // column group: 4 cols each
    int rg = tid >> 5;   // row group: 8 rows each
    int n0 = cg * 4;
    float acc[8][4] = {};

    for (int pass = 0; pass < 2; ++pass) {
        const float* A = pass ? h : agg;
        const float* B = pass ? Wroot : Wrel;
        for (int kc = 0; kc < HID; kc += 16) {
            __syncthreads();
            {   // A tile: 64x16 floats, each thread one float4
                int r = tid >> 2;
                int k4 = (tid & 3) * 4;
                *reinterpret_cast<float4*>(&As[r * 16 + k4]) =
                    *reinterpret_cast<const float4*>(&A[(size_t)(m0 + r) * HID + kc + k4]);
            }
            {   // B tile: 16x128 floats, each thread two float4
                int k = tid >> 5;
                int n = (tid & 31) * 4;
                *reinterpret_cast<float4*>(&Bs[k * HID + n]) =
                    *reinterpret_cast<const float4*>(&B[(size_t)(kc + k) * HID + n]);
                *reinterpret_cast<float4*>(&Bs[(k + 8) * HID + n]) =
                    *reinterpret_cast<const float4*>(&B[(size_t)(kc + k + 8) * HID + n]);
            }
            __syncthreads();
#pragma unroll
            for (int kk = 0; kk < 16; ++kk) {
                float b0 = Bs[kk * HID + n0];
                float b1 = Bs[kk * HID + n0 + 1];
                float b2 = Bs[kk * HID + n0 + 2];
                float b3 = Bs[kk * HID + n0 + 3];
#pragma unroll
                for (int r = 0; r < 8; ++r) {
                    float a = As[(rg * 8 + r) * 16 + kk];
                    acc[r][0] += a * b0;
                    acc[r][1] += a * b1;
                    acc[r][2] += a * b2;
                    acc[r][3] += a * b3;
                }
            }
        }
    }

    float4 bv = *reinterpret_cast<const float4*>(&bias[n0]);
    float* pbase = pooled + (size_t)layer * HID + n0;  // + g*1280 later
    int gprev = -1;
    float p0 = 0.f, p1 = 0.f, p2 = 0.f, p3 = 0.f;
#pragma unroll
    for (int r = 0; r < 8; ++r) {
        int m = m0 + rg * 8 + r;
        float4 o;
        o.x = acc[r][0] + bv.x;
        o.y = acc[r][1] + bv.y;
        o.z = acc[r][2] + bv.z;
        o.w = acc[r][3] + bv.w;
        *reinterpret_cast<float4*>(&hout[(size_t)m * HID + n0]) = o;
        if (m < N_NODES) {
            int g = bmap[m];
            if (g != gprev) {
                if (gprev >= 0) {
                    float* p = pbase + (size_t)gprev * (DEPTH * HID);
                    atomicAdd(p + 0, p0); atomicAdd(p + 1, p1);
                    atomicAdd(p + 2, p2); atomicAdd(p + 3, p3);
                }
                gprev = g; p0 = o.x; p1 = o.y; p2 = o.z; p3 = o.w;
            } else {
                p0 += o.x; p1 += o.y; p2 += o.z; p3 += o.w;
            }
        }
    }
    if (gprev >= 0) {
        float* p = pbase + (size_t)gprev * (DEPTH * HID);
        atomicAdd(p + 0, p0); atomicAdd(p + 1, p1);
        atomicAdd(p + 2, p2); atomicAdd(p + 3, p3);
    }
}

// -------------------- final: out = pooled @ W_sg + b_sg --------------------
__global__ __launch_bounds__(256) void final_kernel(
    const float* __restrict__ pooled, const float* __restrict__ Wsg,
    const float* __restrict__ bsg, float* __restrict__ out) {
    int t = threadIdx.x & 31;
    int g = blockIdx.x * 8 + (threadIdx.x >> 5);
    float acc = bsg[t];
    const float* prow = pooled + (size_t)g * (DEPTH * HID);
    for (int k = 0; k < DEPTH * HID; ++k)
        acc += prow[k] * Wsg[k * IN_F + t];
    out[g * IN_F + t] = acc;
}

extern "C" void kernel_launch(void* const* d_in, const int* in_sizes, int n_in,
                              void* d_out, int out_size, void* d_ws, size_t ws_size,
                              hipStream_t stream) {
    const float* x       = (const float*)d_in[0];
    const int*   edge    = (const int*)d_in[1];
    const int*   bmap    = (const int*)d_in[2];
    // d_in[3] = num_graphs (fixed 512), d_in[8]/d_in[9] = W_ws/b_ws (dead: softmax over dim-1 == 1)
    const float* W_embed = (const float*)d_in[4];
    const float* W_rel   = (const float*)d_in[5];
    const float* b_rel   = (const float*)d_in[6];
    const float* W_root  = (const float*)d_in[7];
    const float* W_sg    = (const float*)d_in[10];
    const float* b_sg    = (const float*)d_in[11];
    float* out = (float*)d_out;

    const int* src = edge;            // edge_index[0]
    const int* dst = edge + N_EDGES;  // edge_index[1]

    char* ws = (char*)d_ws;
    auto alloc = [&](size_t bytes) -> char* {
        char* p = ws;
        ws += (bytes + 255) & ~(size_t)255;
        return p;
    };
    float* h_a       = (float*)alloc((size_t)PADN * HID * 4);
    float* h_b       = (float*)alloc((size_t)PADN * HID * 4);
    float* agg       = (float*)alloc((size_t)PADN * HID * 4);
    float* pooled    = (float*)alloc((size_t)N_GRAPHS * DEPTH * HID * 4);
    int*   counts    = (int*)alloc((size_t)N_NODES * 4);
    int*   row_ptr   = (int*)alloc((size_t)(N_NODES + 1) * 4);
    int*   cursor    = (int*)alloc((size_t)N_NODES * 4);
    int*   sorted_src= (int*)alloc((size_t)N_EDGES * 4);
    int*   bsum      = (int*)alloc((size_t)256 * 4);
    int*   boff      = (int*)alloc((size_t)256 * 4);

    hipMemsetAsync(counts, 0, (size_t)N_NODES * 4, stream);
    hipMemsetAsync(pooled, 0, (size_t)N_GRAPHS * DEPTH * HID * 4, stream);

    embed_kernel<<<1000, 128, 0, stream>>>(x, W_embed, h_a);

    hist_kernel<<<(N_EDGES + 255) / 256, 256, 0, stream>>>(dst, counts, N_EDGES);
    scan_part1<<<NSB, SB, 0, stream>>>(counts, bsum, N_NODES);
    scan_part2<<<1, 256, 0, stream>>>(bsum, boff, NSB);
    scan_part3<<<NSB, SB, 0, stream>>>(counts, boff, row_ptr, cursor, N_NODES);
    scatter_kernel<<<(N_EDGES + 255) / 256, 256, 0, stream>>>(src, dst, cursor, sorted_src);

    float* hc = h_a;
    float* hn = h_b;
    for (int i = 0; i < DEPTH; ++i) {
        aggregate_kernel<<<N_NODES, 128, 0, stream>>>(hc, row_ptr, sorted_src, agg);
        layer_gemm<<<NBLK, 256, 0, stream>>>(agg, hc,
                                             W_rel + (size_t)i * HID * HID,
                                             W_root + (size_t)i * HID * HID,
                                             b_rel + (size_t)i * HID, hn,
                                             bmap, pooled, i);
        float* tmp = hc; hc = hn; hn = tmp;
    }

    final_kernel<<<N_GRAPHS / 8, 256, 0, stream>>>(pooled, W_sg, b_sg, out);
}

// Round 3
// 1037.364 us; speedup vs baseline: 1.6355x; 1.2723x over previous
//
#include <hip/hip_runtime.h>

#define N_NODES 50000
#define N_EDGES 800000
#define HID 128
#define DEPTH 10
#define N_GRAPHS 512
#define IN_F 32

#define BM 128                       // GEMM rows per block
#define GBLK (50048 / BM)            // 391
#define PADN 50048

#define SB 256                       // scan block size
#define NSB ((N_NODES + SB - 1) / SB)     // 196

#define KSTEPS 24                    // virtual K = 768 = 6 terms x 128
#define PACK_CHUNKS (DEPTH * KSTEPS * 512)

typedef __attribute__((ext_vector_type(8))) short short8;
typedef __attribute__((ext_vector_type(4))) float f32x4;

__device__ __forceinline__ float bf2f(short u) {
    union { unsigned i; float f; } v; v.i = ((unsigned)(unsigned short)u) << 16; return v.f;
}
__device__ __forceinline__ short f2bf(float f) {
    union { float f; unsigned i; } v; v.f = f;
    unsigned r = (v.i + 0x7FFFu + ((v.i >> 16) & 1u)) >> 16;
    return (short)r;
}

// -------------------- weight pack: split fp32 W into bf16 hi/lo, MFMA chunk order ----
// Bp layout: [layer][ks(24)][chunk(512)][8 bf16]; chunk = kslot*128 + n;
// chunk holds B[kc + kslot*8 + j][n], j=0..7 (B-fragment order for 16x16x32).
// term = ks>>2: {0:relH, 1:relL, 2:relH, 3:rootH, 4:rootL, 5:rootH}
__global__ __launch_bounds__(256) void pack_weights(
    const float* __restrict__ Wrel, const float* __restrict__ Wroot,
    short* __restrict__ Bp) {
    int idx = blockIdx.x * 256 + threadIdx.x;
    if (idx >= PACK_CHUNKS) return;
    int layer = idx / (KSTEPS * 512);
    int rem = idx - layer * KSTEPS * 512;
    int ks = rem >> 9;
    int c = rem & 511;
    int kslot = c >> 7, n = c & 127;
    int term = ks >> 2;
    int kc = (ks & 3) * 32;
    const float* W = (term < 3 ? Wrel : Wroot) + (size_t)layer * HID * HID;
    bool lo = (term == 1 || term == 4);
    short out[8];
#pragma unroll
    for (int j = 0; j < 8; ++j) {
        int k = kc + kslot * 8 + j;
        float v = W[(size_t)k * HID + n];
        short hi = f2bf(v);
        if (lo) { v = v - bf2f(hi); hi = f2bf(v); }
        out[j] = hi;
    }
    *reinterpret_cast<short8*>(Bp + (size_t)idx * 8) = *reinterpret_cast<short8*>(out);
}

// -------------------- embed: h = x @ W_embed -> bf16 hi/lo planes --------------------
__global__ __launch_bounds__(128) void embed_kernel(
    const float* __restrict__ x, const float* __restrict__ W,
    short* __restrict__ hHp, short* __restrict__ hLp) {
    __shared__ float Ws[IN_F * HID];
    int t = threadIdx.x;
    for (int i = t; i < IN_F * HID; i += 128) Ws[i] = W[i];
    __syncthreads();
    int nbeg = blockIdx.x * 50;
    for (int n = nbeg; n < nbeg + 50; ++n) {
        float acc = 0.f;
#pragma unroll
        for (int k = 0; k < IN_F; ++k)
            acc += x[(size_t)n * IN_F + k] * Ws[k * HID + t];
        short hh = f2bf(acc);
        hHp[(size_t)n * HID + t] = hh;
        hLp[(size_t)n * HID + t] = f2bf(acc - bf2f(hh));
    }
}

// -------------------- CSR build --------------------
__global__ __launch_bounds__(256) void hist_kernel(const int* __restrict__ idx, int* __restrict__ count, int n) {
    int e = blockIdx.x * 256 + threadIdx.x;
    if (e < n) atomicAdd(&count[idx[e]], 1);
}

__global__ __launch_bounds__(SB) void scan_part1(
    const int* __restrict__ count, int* __restrict__ bsum, int n) {
    __shared__ int s[SB];
    int t = threadIdx.x;
    int i = blockIdx.x * SB + t;
    s[t] = (i < n) ? count[i] : 0;
    __syncthreads();
    for (int off = SB / 2; off >= 1; off >>= 1) {
        if (t < off) s[t] += s[t + off];
        __syncthreads();
    }
    if (t == 0) bsum[blockIdx.x] = s[0];
}

__global__ __launch_bounds__(256) void scan_part2(
    const int* __restrict__ bsum, int* __restrict__ boff, int nb) {
    __shared__ int s[256];
    int t = threadIdx.x;
    int v0 = (t < nb) ? bsum[t] : 0;
    s[t] = v0;
    __syncthreads();
    for (int off = 1; off < 256; off <<= 1) {
        int v = (t >= off) ? s[t - off] : 0;
        __syncthreads();
        s[t] += v;
        __syncthreads();
    }
    boff[t] = (t == 0) ? 0 : s[t - 1];
}

__global__ __launch_bounds__(SB) void scan_part3(
    const int* __restrict__ count, const int* __restrict__ boff,
    int* __restrict__ ptr, int* __restrict__ cursor, int n) {
    __shared__ int s[SB];
    int b = blockIdx.x, t = threadIdx.x;
    int i = b * SB + t;
    int v = (i < n) ? count[i] : 0;
    s[t] = v;
    __syncthreads();
    for (int off = 1; off < SB; off <<= 1) {
        int u = (t >= off) ? s[t - off] : 0;
        __syncthreads();
        s[t] += u;
        __syncthreads();
    }
    int excl = s[t] - v + boff[b];
    if (i < n) {
        ptr[i] = excl;
        cursor[i] = excl;
        if (i == n - 1) ptr[n] = excl + v;
    }
}

__global__ __launch_bounds__(256) void scatter_kernel(
    const int* __restrict__ src, const int* __restrict__ dst,
    int* __restrict__ cursor, int* __restrict__ sorted_src) {
    int e = blockIdx.x * 256 + threadIdx.x;
    if (e < N_EDGES) {
        int p = atomicAdd(&cursor[dst[e]], 1);
        sorted_src[p] = src[e];
    }
}

// -------------------- aggregate: agg[n] = sum_j (hH+hL)[src[j]] -> hi/lo planes ------
__global__ __launch_bounds__(128) void aggregate_kernel(
    const short* __restrict__ hHp, const short* __restrict__ hLp,
    const int* __restrict__ row_ptr, const int* __restrict__ sorted_src,
    short* __restrict__ aggHp, short* __restrict__ aggLp) {
    int n = blockIdx.x;
    int t = threadIdx.x;  // one feature per thread, 256B coalesced row reads per plane
    int beg = row_ptr[n], end = row_ptr[n + 1];
    float acc = 0.f;
    int j = beg;
    for (; j + 4 <= end; j += 4) {
        int s0 = sorted_src[j], s1 = sorted_src[j + 1], s2 = sorted_src[j + 2], s3 = sorted_src[j + 3];
        acc += bf2f(hHp[(size_t)s0 * HID + t]) + bf2f(hLp[(size_t)s0 * HID + t]);
        acc += bf2f(hHp[(size_t)s1 * HID + t]) + bf2f(hLp[(size_t)s1 * HID + t]);
        acc += bf2f(hHp[(size_t)s2 * HID + t]) + bf2f(hLp[(size_t)s2 * HID + t]);
        acc += bf2f(hHp[(size_t)s3 * HID + t]) + bf2f(hLp[(size_t)s3 * HID + t]);
    }
    for (; j < end; ++j) {
        int s = sorted_src[j];
        acc += bf2f(hHp[(size_t)s * HID + t]) + bf2f(hLp[(size_t)s * HID + t]);
    }
    short hh = f2bf(acc);
    aggHp[(size_t)n * HID + t] = hh;
    aggLp[(size_t)n * HID + t] = f2bf(acc - bf2f(hh));
}

// -------------------- MFMA layer GEMM --------------------
// C(128x128 tile) = sum over virtual K=768: [aggH,aggH,aggL,hH,hH,hL] x packed B terms.
// 4 waves in 2x2 grid, each wave 64x64 = 4x4 fragments of 16x16x32 bf16 MFMA.
// LDS tiles kslot-major: chunk (kslot*128 + row) of 8 bf16 -> frag reads bank-uniform.
__global__ __launch_bounds__(256) void layer_gemm_mfma(
    const short* __restrict__ aggH, const short* __restrict__ aggL,
    const short* __restrict__ hH, const short* __restrict__ hL,
    const short* __restrict__ Bp, const float* __restrict__ bias,
    short* __restrict__ outH, short* __restrict__ outL,
    const int* __restrict__ bmap, float* __restrict__ pooled, int layer) {
    __shared__ __align__(16) short Ab[2][4096];
    __shared__ __align__(16) short Bb[2][4096];
    int tid = threadIdx.x;
    int lane = tid & 63;
    int w = tid >> 6;
    int wr = w >> 1, wc = w & 1;
    int m0 = blockIdx.x * BM;

    // staging: 512 chunks per tile, 2 per thread; row = idx>>2, kslot = idx&3
    // -> global A reads are 64B-line-exact (4 lanes cover one row's 64B)
    int i0 = tid, i1 = tid + 256;
    int r0 = i0 >> 2, q0 = i0 & 3;
    int r1 = i1 >> 2, q1 = i1 & 3;

    f32x4 acc[4][4];
#pragma unroll
    for (int m = 0; m < 4; ++m)
#pragma unroll
        for (int n = 0; n < 4; ++n) acc[m][n] = (f32x4)0.f;

    // prologue: stage ks=0 (term 0: aggH, kc=0)
    {
        short8 a0 = *reinterpret_cast<const short8*>(aggH + (size_t)(m0 + r0) * HID + q0 * 8);
        short8 a1 = *reinterpret_cast<const short8*>(aggH + (size_t)(m0 + r1) * HID + q1 * 8);
        short8 b0 = *reinterpret_cast<const short8*>(Bp + (size_t)i0 * 8);
        short8 b1 = *reinterpret_cast<const short8*>(Bp + (size_t)i1 * 8);
        *reinterpret_cast<short8*>(&Ab[0][(q0 * 128 + r0) * 8]) = a0;
        *reinterpret_cast<short8*>(&Ab[0][(q1 * 128 + r1) * 8]) = a1;
        *reinterpret_cast<short8*>(&Bb[0][i0 * 8]) = b0;
        *reinterpret_cast<short8*>(&Bb[0][i1 * 8]) = b1;
    }
    __syncthreads();

    int kb = lane >> 4;   // kslot within k-step
    int rr = lane & 15;

    for (int ks = 0; ks < KSTEPS; ++ks) {
        int cur = ks & 1;
        short8 a0, a1, b0, b1;
        if (ks < KSTEPS - 1) {
            int nks = ks + 1;
            int term = nks >> 2;
            int kc = (nks & 3) * 32;
            const short* Ap = term <= 1 ? aggH : term == 2 ? aggL : term <= 4 ? hH : hL;
            a0 = *reinterpret_cast<const short8*>(Ap + (size_t)(m0 + r0) * HID + kc + q0 * 8);
            a1 = *reinterpret_cast<const short8*>(Ap + (size_t)(m0 + r1) * HID + kc + q1 * 8);
            const short* Bsrc = Bp + (size_t)nks * 4096;
            b0 = *reinterpret_cast<const short8*>(Bsrc + (size_t)i0 * 8);
            b1 = *reinterpret_cast<const short8*>(Bsrc + (size_t)i1 * 8);
        }
        short8 af[4], bfr[4];
#pragma unroll
        for (int m = 0; m < 4; ++m)
            af[m] = *reinterpret_cast<const short8*>(&Ab[cur][(kb * 128 + wr * 64 + m * 16 + rr) * 8]);
#pragma unroll
        for (int n = 0; n < 4; ++n)
            bfr[n] = *reinterpret_cast<const short8*>(&Bb[cur][(kb * 128 + wc * 64 + n * 16 + rr) * 8]);
#pragma unroll
        for (int m = 0; m < 4; ++m)
#pragma unroll
            for (int n = 0; n < 4; ++n)
                acc[m][n] = __builtin_amdgcn_mfma_f32_16x16x32_bf16(af[m], bfr[n], acc[m][n], 0, 0, 0);
        if (ks < KSTEPS - 1) {
            int nb = cur ^ 1;
            *reinterpret_cast<short8*>(&Ab[nb][(q0 * 128 + r0) * 8]) = a0;
            *reinterpret_cast<short8*>(&Ab[nb][(q1 * 128 + r1) * 8]) = a1;
            *reinterpret_cast<short8*>(&Bb[nb][i0 * 8]) = b0;
            *reinterpret_cast<short8*>(&Bb[nb][i1 * 8]) = b1;
        }
        __syncthreads();
    }

    // epilogue: bias, split-bf16 store, fused sorted-run pooling
    int col = wc * 64 + rr;
    float bs[4];
#pragma unroll
    for (int n = 0; n < 4; ++n) bs[n] = bias[col + n * 16];
    float* pbase = pooled + (size_t)layer * HID + col;
    int rb = m0 + wr * 64 + (lane >> 4) * 4;
    int gprev = -1;
    float p0 = 0.f, p1 = 0.f, p2 = 0.f, p3 = 0.f;
#pragma unroll
    for (int m = 0; m < 4; ++m) {
#pragma unroll
        for (int i = 0; i < 4; ++i) {
            int row = rb + m * 16 + i;
            float v0 = acc[m][0][i] + bs[0];
            float v1 = acc[m][1][i] + bs[1];
            float v2 = acc[m][2][i] + bs[2];
            float v3 = acc[m][3][i] + bs[3];
            size_t off = (size_t)row * HID + col;
            short h0 = f2bf(v0); outH[off]      = h0; outL[off]      = f2bf(v0 - bf2f(h0));
            short h1 = f2bf(v1); outH[off + 16] = h1; outL[off + 16] = f2bf(v1 - bf2f(h1));
            short h2 = f2bf(v2); outH[off + 32] = h2; outL[off + 32] = f2bf(v2 - bf2f(h2));
            short h3 = f2bf(v3); outH[off + 48] = h3; outL[off + 48] = f2bf(v3 - bf2f(h3));
            if (row < N_NODES) {
                int g = bmap[row];
                if (g != gprev) {
                    if (gprev >= 0) {
                        float* p = pbase + (size_t)gprev * (DEPTH * HID);
                        atomicAdd(p, p0); atomicAdd(p + 16, p1);
                        atomicAdd(p + 32, p2); atomicAdd(p + 48, p3);
                    }
                    gprev = g; p0 = v0; p1 = v1; p2 = v2; p3 = v3;
                } else {
                    p0 += v0; p1 += v1; p2 += v2; p3 += v3;
                }
            }
        }
    }
    if (gprev >= 0) {
        float* p = pbase + (size_t)gprev * (DEPTH * HID);
        atomicAdd(p, p0); atomicAdd(p + 16, p1);
        atomicAdd(p + 32, p2); atomicAdd(p + 48, p3);
    }
}

// -------------------- final: out = pooled @ W_sg + b_sg --------------------
__global__ __launch_bounds__(256) void final_kernel(
    const float* __restrict__ pooled, const float* __restrict__ Wsg,
    const float* __restrict__ bsg, float* __restrict__ out) {
    int t = threadIdx.x & 31;
    int g = blockIdx.x * 8 + (threadIdx.x >> 5);
    float acc = bsg[t];
    const float* prow = pooled + (size_t)g * (DEPTH * HID);
    for (int k = 0; k < DEPTH * HID; ++k)
        acc += prow[k] * Wsg[k * IN_F + t];
    out[g * IN_F + t] = acc;
}

extern "C" void kernel_launch(void* const* d_in, const int* in_sizes, int n_in,
                              void* d_out, int out_size, void* d_ws, size_t ws_size,
                              hipStream_t stream) {
    const float* x       = (const float*)d_in[0];
    const int*   edge    = (const int*)d_in[1];
    const int*   bmap    = (const int*)d_in[2];
    // d_in[3] = num_graphs (512); d_in[8]/d_in[9] = W_ws/b_ws dead (softmax over dim-1 == 1)
    const float* W_embed = (const float*)d_in[4];
    const float* W_rel   = (const float*)d_in[5];
    const float* b_rel   = (const float*)d_in[6];
    const float* W_root  = (const float*)d_in[7];
    const float* W_sg    = (const float*)d_in[10];
    const float* b_sg    = (const float*)d_in[11];
    float* out = (float*)d_out;

    const int* src = edge;
    const int* dst = edge + N_EDGES;

    char* ws = (char*)d_ws;
    auto alloc = [&](size_t bytes) -> char* {
        char* p = ws;
        ws += (bytes + 255) & ~(size_t)255;
        return p;
    };
    const size_t planeB = (size_t)PADN * HID * 2;  // bf16 plane
    short* hH_a  = (short*)alloc(planeB);
    short* hL_a  = (short*)alloc(planeB);
    short* hH_b  = (short*)alloc(planeB);
    short* hL_b  = (short*)alloc(planeB);
    short* aggH  = (short*)alloc(planeB);
    short* aggL  = (short*)alloc(planeB);
    float* pooled = (float*)alloc((size_t)N_GRAPHS * DEPTH * HID * 4);
    int* counts     = (int*)alloc((size_t)N_NODES * 4);
    int* row_ptr    = (int*)alloc((size_t)(N_NODES + 1) * 4);
    int* cursor     = (int*)alloc((size_t)N_NODES * 4);
    int* sorted_src = (int*)alloc((size_t)N_EDGES * 4);
    int* bsum       = (int*)alloc((size_t)256 * 4);
    int* boff       = (int*)alloc((size_t)256 * 4);
    short* Bpacked  = (short*)alloc((size_t)PACK_CHUNKS * 8 * 2);

    hipMemsetAsync(counts, 0, (size_t)N_NODES * 4, stream);
    hipMemsetAsync(pooled, 0, (size_t)N_GRAPHS * DEPTH * HID * 4, stream);

    pack_weights<<<(PACK_CHUNKS + 255) / 256, 256, 0, stream>>>(W_rel, W_root, Bpacked);
    embed_kernel<<<1000, 128, 0, stream>>>(x, W_embed, hH_a, hL_a);

    hist_kernel<<<(N_EDGES + 255) / 256, 256, 0, stream>>>(dst, counts, N_EDGES);
    scan_part1<<<NSB, SB, 0, stream>>>(counts, bsum, N_NODES);
    scan_part2<<<1, 256, 0, stream>>>(bsum, boff, NSB);
    scan_part3<<<NSB, SB, 0, stream>>>(counts, boff, row_ptr, cursor, N_NODES);
    scatter_kernel<<<(N_EDGES + 255) / 256, 256, 0, stream>>>(src, dst, cursor, sorted_src);

    short *hcH = hH_a, *hcL = hL_a, *hnH = hH_b, *hnL = hL_b;
    for (int i = 0; i < DEPTH; ++i) {
        aggregate_kernel<<<N_NODES, 128, 0, stream>>>(hcH, hcL, row_ptr, sorted_src, aggH, aggL);
        layer_gemm_mfma<<<GBLK, 256, 0, stream>>>(aggH, aggL, hcH, hcL,
                                                  Bpacked + (size_t)i * KSTEPS * 4096,
                                                  b_rel + (size_t)i * HID,
                                                  hnH, hnL, bmap, pooled, i);
        short* t;
        t = hcH; hcH = hnH; hnH = t;
        t = hcL; hcL = hnL; hnL = t;
    }

    final_kernel<<<N_GRAPHS / 8, 256, 0, stream>>>(pooled, W_sg, b_sg, out);
}

// Round 4
// 1014.309 us; speedup vs baseline: 1.6727x; 1.0227x over previous
//
#include <hip/hip_runtime.h>

#define N_NODES 50000
#define N_EDGES 800000
#define HID 128
#define DEPTH 10
#define N_GRAPHS 512
#define IN_F 32

#define BM 128                       // GEMM rows per block
#define GBLK (50048 / BM)            // 391
#define PADN 50048

#define SB 256                       // scan block size
#define NSB ((N_NODES + SB - 1) / SB)     // 196

#define KSTEPS 24                    // virtual K = 768 = 6 terms x 128
#define PACK_CHUNKS (DEPTH * KSTEPS * 512)

typedef __attribute__((ext_vector_type(8))) short short8;
typedef __attribute__((ext_vector_type(4))) float f32x4;

__device__ __forceinline__ float bf2f(short u) {
    union { unsigned i; float f; } v; v.i = ((unsigned)(unsigned short)u) << 16; return v.f;
}
__device__ __forceinline__ short f2bf(float f) {
    union { float f; unsigned i; } v; v.f = f;
    unsigned r = (v.i + 0x7FFFu + ((v.i >> 16) & 1u)) >> 16;
    return (short)r;
}

// -------------------- weight pack: split fp32 W into bf16 hi/lo, MFMA chunk order ----
// Bp layout: [layer][ks(24)][chunk(512)][8 bf16]; chunk = kslot*128 + n;
// chunk holds B[kc + kslot*8 + j][n], j=0..7 (B-fragment order for 16x16x32).
// term = ks>>2: {0:relH, 1:relL, 2:relH, 3:rootH, 4:rootL, 5:rootH}
__global__ __launch_bounds__(256) void pack_weights(
    const float* __restrict__ Wrel, const float* __restrict__ Wroot,
    short* __restrict__ Bp) {
    int idx = blockIdx.x * 256 + threadIdx.x;
    if (idx >= PACK_CHUNKS) return;
    int layer = idx / (KSTEPS * 512);
    int rem = idx - layer * KSTEPS * 512;
    int ks = rem >> 9;
    int c = rem & 511;
    int kslot = c >> 7, n = c & 127;
    int term = ks >> 2;
    int kc = (ks & 3) * 32;
    const float* W = (term < 3 ? Wrel : Wroot) + (size_t)layer * HID * HID;
    bool lo = (term == 1 || term == 4);
    short out[8];
#pragma unroll
    for (int j = 0; j < 8; ++j) {
        int k = kc + kslot * 8 + j;
        float v = W[(size_t)k * HID + n];
        short hi = f2bf(v);
        if (lo) { v = v - bf2f(hi); hi = f2bf(v); }
        out[j] = hi;
    }
    *reinterpret_cast<short8*>(Bp + (size_t)idx * 8) = *reinterpret_cast<short8*>(out);
}

// -------------------- embed: h = x @ W_embed -> bf16 hi/lo planes --------------------
__global__ __launch_bounds__(128) void embed_kernel(
    const float* __restrict__ x, const float* __restrict__ W,
    short* __restrict__ hHp, short* __restrict__ hLp) {
    __shared__ float Ws[IN_F * HID];
    int t = threadIdx.x;
    for (int i = t; i < IN_F * HID; i += 128) Ws[i] = W[i];
    __syncthreads();
    int nbeg = blockIdx.x * 50;
    for (int n = nbeg; n < nbeg + 50; ++n) {
        float acc = 0.f;
#pragma unroll
        for (int k = 0; k < IN_F; ++k)
            acc += x[(size_t)n * IN_F + k] * Ws[k * HID + t];
        short hh = f2bf(acc);
        hHp[(size_t)n * HID + t] = hh;
        hLp[(size_t)n * HID + t] = f2bf(acc - bf2f(hh));
    }
}

// -------------------- CSR build --------------------
__global__ __launch_bounds__(256) void hist_kernel(const int* __restrict__ idx, int* __restrict__ count, int n) {
    int e = blockIdx.x * 256 + threadIdx.x;
    if (e < n) atomicAdd(&count[idx[e]], 1);
}

__global__ __launch_bounds__(SB) void scan_part1(
    const int* __restrict__ count, int* __restrict__ bsum, int n) {
    __shared__ int s[SB];
    int t = threadIdx.x;
    int i = blockIdx.x * SB + t;
    s[t] = (i < n) ? count[i] : 0;
    __syncthreads();
    for (int off = SB / 2; off >= 1; off >>= 1) {
        if (t < off) s[t] += s[t + off];
        __syncthreads();
    }
    if (t == 0) bsum[blockIdx.x] = s[0];
}

__global__ __launch_bounds__(256) void scan_part2(
    const int* __restrict__ bsum, int* __restrict__ boff, int nb) {
    __shared__ int s[256];
    int t = threadIdx.x;
    int v0 = (t < nb) ? bsum[t] : 0;
    s[t] = v0;
    __syncthreads();
    for (int off = 1; off < 256; off <<= 1) {
        int v = (t >= off) ? s[t - off] : 0;
        __syncthreads();
        s[t] += v;
        __syncthreads();
    }
    boff[t] = (t == 0) ? 0 : s[t - 1];
}

__global__ __launch_bounds__(SB) void scan_part3(
    const int* __restrict__ count, const int* __restrict__ boff,
    int* __restrict__ ptr, int* __restrict__ cursor, int n) {
    __shared__ int s[SB];
    int b = blockIdx.x, t = threadIdx.x;
    int i = b * SB + t;
    int v = (i < n) ? count[i] : 0;
    s[t] = v;
    __syncthreads();
    for (int off = 1; off < SB; off <<= 1) {
        int u = (t >= off) ? s[t - off] : 0;
        __syncthreads();
        s[t] += u;
        __syncthreads();
    }
    int excl = s[t] - v + boff[b];
    if (i < n) {
        ptr[i] = excl;
        cursor[i] = excl;
        if (i == n - 1) ptr[n] = excl + v;
    }
}

__global__ __launch_bounds__(256) void scatter_kernel(
    const int* __restrict__ src, const int* __restrict__ dst,
    int* __restrict__ cursor, int* __restrict__ sorted_src) {
    int e = blockIdx.x * 256 + threadIdx.x;
    if (e < N_EDGES) {
        int p = atomicAdd(&cursor[dst[e]], 1);
        sorted_src[p] = src[e];
    }
}

// -------------------- aggregate: wave-per-node gather --------------------
// 64 lanes x 2 features (dword = packed {f,f+1} bf16 pair per plane).
// Indices broadcast to SGPR via readfirstlane -> scalar address path.
// Unroll-8: 16 outstanding vector loads per wave to hide L2/L3 latency.
__global__ __launch_bounds__(256) void aggregate_kernel(
    const short* __restrict__ hHp, const short* __restrict__ hLp,
    const int* __restrict__ row_ptr, const int* __restrict__ sorted_src,
    short* __restrict__ aggHp, short* __restrict__ aggLp) {
    int n = (blockIdx.x * 256 + threadIdx.x) >> 6;   // node = global wave id
    int lane = threadIdx.x & 63;
    const unsigned* __restrict__ H = (const unsigned*)hHp;
    const unsigned* __restrict__ L = (const unsigned*)hLp;
    int beg = row_ptr[n], end = row_ptr[n + 1];
    float a0 = 0.f, a1 = 0.f;
#define ACC(hv, lv) do { \
        union { unsigned u; float f; } t0, t1, t2, t3; \
        t0.u = (hv) << 16; t1.u = (hv) & 0xFFFF0000u; \
        t2.u = (lv) << 16; t3.u = (lv) & 0xFFFF0000u; \
        a0 += t0.f + t2.f; a1 += t1.f + t3.f; } while (0)
    int j = beg;
    for (; j + 8 <= end; j += 8) {
        unsigned hv[8], lv[8];
#pragma unroll
        for (int u = 0; u < 8; ++u) {
            int s = __builtin_amdgcn_readfirstlane(sorted_src[j + u]);
            size_t ro = (size_t)s * (HID / 2) + lane;
            hv[u] = H[ro]; lv[u] = L[ro];
        }
#pragma unroll
        for (int u = 0; u < 8; ++u) ACC(hv[u], lv[u]);
    }
    for (; j + 2 <= end; j += 2) {
        int s0 = __builtin_amdgcn_readfirstlane(sorted_src[j]);
        int s1 = __builtin_amdgcn_readfirstlane(sorted_src[j + 1]);
        unsigned h0 = H[(size_t)s0 * (HID / 2) + lane], l0 = L[(size_t)s0 * (HID / 2) + lane];
        unsigned h1 = H[(size_t)s1 * (HID / 2) + lane], l1 = L[(size_t)s1 * (HID / 2) + lane];
        ACC(h0, l0); ACC(h1, l1);
    }
    if (j < end) {
        int s = __builtin_amdgcn_readfirstlane(sorted_src[j]);
        unsigned hv = H[(size_t)s * (HID / 2) + lane], lv = L[(size_t)s * (HID / 2) + lane];
        ACC(hv, lv);
    }
#undef ACC
    short p0 = f2bf(a0), p1 = f2bf(a1);
    float r0 = a0 - bf2f(p0), r1 = a1 - bf2f(p1);
    unsigned hw = ((unsigned)(unsigned short)p1 << 16) | (unsigned)(unsigned short)p0;
    unsigned lw = ((unsigned)(unsigned short)f2bf(r1) << 16) | (unsigned)(unsigned short)f2bf(r0);
    ((unsigned*)aggHp)[(size_t)n * (HID / 2) + lane] = hw;
    ((unsigned*)aggLp)[(size_t)n * (HID / 2) + lane] = lw;
}

// -------------------- MFMA layer GEMM --------------------
// C(128x128 tile) = sum over virtual K=768: [aggH,aggH,aggL,hH,hH,hL] x packed B terms.
// 4 waves in 2x2 grid, each wave 64x64 = 4x4 fragments of 16x16x32 bf16 MFMA.
__global__ __launch_bounds__(256) void layer_gemm_mfma(
    const short* __restrict__ aggH, const short* __restrict__ aggL,
    const short* __restrict__ hH, const short* __restrict__ hL,
    const short* __restrict__ Bp, const float* __restrict__ bias,
    short* __restrict__ outH, short* __restrict__ outL,
    const int* __restrict__ bmap, float* __restrict__ pooled, int layer) {
    __shared__ __align__(16) short Ab[2][4096];
    __shared__ __align__(16) short Bb[2][4096];
    int tid = threadIdx.x;
    int lane = tid & 63;
    int w = tid >> 6;
    int wr = w >> 1, wc = w & 1;
    int m0 = blockIdx.x * BM;

    int i0 = tid, i1 = tid + 256;
    int r0 = i0 >> 2, q0 = i0 & 3;
    int r1 = i1 >> 2, q1 = i1 & 3;

    f32x4 acc[4][4];
#pragma unroll
    for (int m = 0; m < 4; ++m)
#pragma unroll
        for (int n = 0; n < 4; ++n) acc[m][n] = (f32x4)0.f;

    {
        short8 a0 = *reinterpret_cast<const short8*>(aggH + (size_t)(m0 + r0) * HID + q0 * 8);
        short8 a1 = *reinterpret_cast<const short8*>(aggH + (size_t)(m0 + r1) * HID + q1 * 8);
        short8 b0 = *reinterpret_cast<const short8*>(Bp + (size_t)i0 * 8);
        short8 b1 = *reinterpret_cast<const short8*>(Bp + (size_t)i1 * 8);
        *reinterpret_cast<short8*>(&Ab[0][(q0 * 128 + r0) * 8]) = a0;
        *reinterpret_cast<short8*>(&Ab[0][(q1 * 128 + r1) * 8]) = a1;
        *reinterpret_cast<short8*>(&Bb[0][i0 * 8]) = b0;
        *reinterpret_cast<short8*>(&Bb[0][i1 * 8]) = b1;
    }
    __syncthreads();

    int kb = lane >> 4;
    int rr = lane & 15;

    for (int ks = 0; ks < KSTEPS; ++ks) {
        int cur = ks & 1;
        short8 a0, a1, b0, b1;
        if (ks < KSTEPS - 1) {
            int nks = ks + 1;
            int term = nks >> 2;
            int kc = (nks & 3) * 32;
            const short* Ap = term <= 1 ? aggH : term == 2 ? aggL : term <= 4 ? hH : hL;
            a0 = *reinterpret_cast<const short8*>(Ap + (size_t)(m0 + r0) * HID + kc + q0 * 8);
            a1 = *reinterpret_cast<const short8*>(Ap + (size_t)(m0 + r1) * HID + kc + q1 * 8);
            const short* Bsrc = Bp + (size_t)nks * 4096;
            b0 = *reinterpret_cast<const short8*>(Bsrc + (size_t)i0 * 8);
            b1 = *reinterpret_cast<const short8*>(Bsrc + (size_t)i1 * 8);
        }
        short8 af[4], bfr[4];
#pragma unroll
        for (int m = 0; m < 4; ++m)
            af[m] = *reinterpret_cast<const short8*>(&Ab[cur][(kb * 128 + wr * 64 + m * 16 + rr) * 8]);
#pragma unroll
        for (int n = 0; n < 4; ++n)
            bfr[n] = *reinterpret_cast<const short8*>(&Bb[cur][(kb * 128 + wc * 64 + n * 16 + rr) * 8]);
#pragma unroll
        for (int m = 0; m < 4; ++m)
#pragma unroll
            for (int n = 0; n < 4; ++n)
                acc[m][n] = __builtin_amdgcn_mfma_f32_16x16x32_bf16(af[m], bfr[n], acc[m][n], 0, 0, 0);
        if (ks < KSTEPS - 1) {
            int nb = cur ^ 1;
            *reinterpret_cast<short8*>(&Ab[nb][(q0 * 128 + r0) * 8]) = a0;
            *reinterpret_cast<short8*>(&Ab[nb][(q1 * 128 + r1) * 8]) = a1;
            *reinterpret_cast<short8*>(&Bb[nb][i0 * 8]) = b0;
            *reinterpret_cast<short8*>(&Bb[nb][i1 * 8]) = b1;
        }
        __syncthreads();
    }

    int col = wc * 64 + rr;
    float bs[4];
#pragma unroll
    for (int n = 0; n < 4; ++n) bs[n] = bias[col + n * 16];
    float* pbase = pooled + (size_t)layer * HID + col;
    int rb = m0 + wr * 64 + (lane >> 4) * 4;
    int gprev = -1;
    float p0 = 0.f, p1 = 0.f, p2 = 0.f, p3 = 0.f;
#pragma unroll
    for (int m = 0; m < 4; ++m) {
#pragma unroll
        for (int i = 0; i < 4; ++i) {
            int row = rb + m * 16 + i;
            float v0 = acc[m][0][i] + bs[0];
            float v1 = acc[m][1][i] + bs[1];
            float v2 = acc[m][2][i] + bs[2];
            float v3 = acc[m][3][i] + bs[3];
            size_t off = (size_t)row * HID + col;
            short h0 = f2bf(v0); outH[off]      = h0; outL[off]      = f2bf(v0 - bf2f(h0));
            short h1 = f2bf(v1); outH[off + 16] = h1; outL[off + 16] = f2bf(v1 - bf2f(h1));
            short h2 = f2bf(v2); outH[off + 32] = h2; outL[off + 32] = f2bf(v2 - bf2f(h2));
            short h3 = f2bf(v3); outH[off + 48] = h3; outL[off + 48] = f2bf(v3 - bf2f(h3));
            if (row < N_NODES) {
                int g = bmap[row];
                if (g != gprev) {
                    if (gprev >= 0) {
                        float* p = pbase + (size_t)gprev * (DEPTH * HID);
                        atomicAdd(p, p0); atomicAdd(p + 16, p1);
                        atomicAdd(p + 32, p2); atomicAdd(p + 48, p3);
                    }
                    gprev = g; p0 = v0; p1 = v1; p2 = v2; p3 = v3;
                } else {
                    p0 += v0; p1 += v1; p2 += v2; p3 += v3;
                }
            }
        }
    }
    if (gprev >= 0) {
        float* p = pbase + (size_t)gprev * (DEPTH * HID);
        atomicAdd(p, p0); atomicAdd(p + 16, p1);
        atomicAdd(p + 32, p2); atomicAdd(p + 48, p3);
    }
}

// -------------------- final: out = pooled @ W_sg + b_sg --------------------
__global__ __launch_bounds__(256) void final_kernel(
    const float* __restrict__ pooled, const float* __restrict__ Wsg,
    const float* __restrict__ bsg, float* __restrict__ out) {
    int t = threadIdx.x & 31;
    int g = blockIdx.x * 8 + (threadIdx.x >> 5);
    float acc = bsg[t];
    const float* prow = pooled + (size_t)g * (DEPTH * HID);
    for (int k = 0; k < DEPTH * HID; ++k)
        acc += prow[k] * Wsg[k * IN_F + t];
    out[g * IN_F + t] = acc;
}

extern "C" void kernel_launch(void* const* d_in, const int* in_sizes, int n_in,
                              void* d_out, int out_size, void* d_ws, size_t ws_size,
                              hipStream_t stream) {
    const float* x       = (const float*)d_in[0];
    const int*   edge    = (const int*)d_in[1];
    const int*   bmap    = (const int*)d_in[2];
    // d_in[3] = num_graphs (512); d_in[8]/d_in[9] = W_ws/b_ws dead (softmax over dim-1 == 1)
    const float* W_embed = (const float*)d_in[4];
    const float* W_rel   = (const float*)d_in[5];
    const float* b_rel   = (const float*)d_in[6];
    const float* W_root  = (const float*)d_in[7];
    const float* W_sg    = (const float*)d_in[10];
    const float* b_sg    = (const float*)d_in[11];
    float* out = (float*)d_out;

    const int* src = edge;
    const int* dst = edge + N_EDGES;

    char* ws = (char*)d_ws;
    auto alloc = [&](size_t bytes) -> char* {
        char* p = ws;
        ws += (bytes + 255) & ~(size_t)255;
        return p;
    };
    const size_t planeB = (size_t)PADN * HID * 2;  // bf16 plane
    short* hH_a  = (short*)alloc(planeB);
    short* hL_a  = (short*)alloc(planeB);
    short* hH_b  = (short*)alloc(planeB);
    short* hL_b  = (short*)alloc(planeB);
    short* aggH  = (short*)alloc(planeB);
    short* aggL  = (short*)alloc(planeB);
    float* pooled = (float*)alloc((size_t)N_GRAPHS * DEPTH * HID * 4);
    int* counts     = (int*)alloc((size_t)N_NODES * 4);
    int* row_ptr    = (int*)alloc((size_t)(N_NODES + 1) * 4);
    int* cursor     = (int*)alloc((size_t)N_NODES * 4);
    int* sorted_src = (int*)alloc((size_t)N_EDGES * 4);
    int* bsum       = (int*)alloc((size_t)256 * 4);
    int* boff       = (int*)alloc((size_t)256 * 4);
    short* Bpacked  = (short*)alloc((size_t)PACK_CHUNKS * 8 * 2);

    hipMemsetAsync(counts, 0, (size_t)N_NODES * 4, stream);
    hipMemsetAsync(pooled, 0, (size_t)N_GRAPHS * DEPTH * HID * 4, stream);

    pack_weights<<<(PACK_CHUNKS + 255) / 256, 256, 0, stream>>>(W_rel, W_root, Bpacked);
    embed_kernel<<<1000, 128, 0, stream>>>(x, W_embed, hH_a, hL_a);

    hist_kernel<<<(N_EDGES + 255) / 256, 256, 0, stream>>>(dst, counts, N_EDGES);
    scan_part1<<<NSB, SB, 0, stream>>>(counts, bsum, N_NODES);
    scan_part2<<<1, 256, 0, stream>>>(bsum, boff, NSB);
    scan_part3<<<NSB, SB, 0, stream>>>(counts, boff, row_ptr, cursor, N_NODES);
    scatter_kernel<<<(N_EDGES + 255) / 256, 256, 0, stream>>>(src, dst, cursor, sorted_src);

    short *hcH = hH_a, *hcL = hL_a, *hnH = hH_b, *hnL = hL_b;
    for (int i = 0; i < DEPTH; ++i) {
        aggregate_kernel<<<(N_NODES + 3) / 4, 256, 0, stream>>>(hcH, hcL, row_ptr, sorted_src, aggH, aggL);
        layer_gemm_mfma<<<GBLK, 256, 0, stream>>>(aggH, aggL, hcH, hcL,
                                                  Bpacked + (size_t)i * KSTEPS * 4096,
                                                  b_rel + (size_t)i * HID,
                                                  hnH, hnL, bmap, pooled, i);
        short* t;
        t = hcH; hcH = hnH; hnH = t;
        t = hcL; hcL = hnL; hnL = t;
    }

    final_kernel<<<N_GRAPHS / 8, 256, 0, stream>>>(pooled, W_sg, b_sg, out);
}

// Round 5
// 1003.069 us; speedup vs baseline: 1.6914x; 1.0112x over previous
//
#include <hip/hip_runtime.h>

#define N_NODES 50000
#define N_EDGES 800000
#define HID 128
#define DEPTH 10
#define N_GRAPHS 512
#define IN_F 32

#define BM 128                       // GEMM rows per block
#define GBLK (50048 / BM)            // 391
#define PADN 50048

#define ROWW 256                     // interleaved row width in shorts: [H 128 | L 128]

#define SB 256                       // scan block size
#define NSB ((N_NODES + SB - 1) / SB)     // 196

#define KSTEPS 24                    // virtual K = 768 = 6 terms x 128
#define PACK_CHUNKS (DEPTH * KSTEPS * 512)

typedef __attribute__((ext_vector_type(8))) short short8;
typedef __attribute__((ext_vector_type(4))) float f32x4;
typedef __attribute__((ext_vector_type(2))) unsigned uint2v;
typedef __attribute__((ext_vector_type(4))) unsigned uint4v;

__device__ __forceinline__ float bf2f(short u) {
    union { unsigned i; float f; } v; v.i = ((unsigned)(unsigned short)u) << 16; return v.f;
}
__device__ __forceinline__ short f2bf(float f) {
    union { float f; unsigned i; } v; v.f = f;
    unsigned r = (v.i + 0x7FFFu + ((v.i >> 16) & 1u)) >> 16;
    return (short)r;
}

// -------------------- weight pack (unchanged layout) --------------------
// Bp: [layer][ks(24)][chunk(512)][8 bf16]; chunk = kslot*128 + n;
// term = ks>>2: B-plane {0:relH,1:relL,2:relH,3:rootH,4:rootL,5:rootH}
__global__ __launch_bounds__(256) void pack_weights(
    const float* __restrict__ Wrel, const float* __restrict__ Wroot,
    short* __restrict__ Bp) {
    int idx = blockIdx.x * 256 + threadIdx.x;
    if (idx >= PACK_CHUNKS) return;
    int layer = idx / (KSTEPS * 512);
    int rem = idx - layer * KSTEPS * 512;
    int ks = rem >> 9;
    int c = rem & 511;
    int kslot = c >> 7, n = c & 127;
    int term = ks >> 2;
    int kc = (ks & 3) * 32;
    const float* W = (term < 3 ? Wrel : Wroot) + (size_t)layer * HID * HID;
    bool lo = (term == 1 || term == 4);
    short out[8];
#pragma unroll
    for (int j = 0; j < 8; ++j) {
        int k = kc + kslot * 8 + j;
        float v = W[(size_t)k * HID + n];
        short hi = f2bf(v);
        if (lo) { v = v - bf2f(hi); hi = f2bf(v); }
        out[j] = hi;
    }
    *reinterpret_cast<short8*>(Bp + (size_t)idx * 8) = *reinterpret_cast<short8*>(out);
}

// -------------------- embed -> interleaved [H|L] rows --------------------
__global__ __launch_bounds__(128) void embed_kernel(
    const float* __restrict__ x, const float* __restrict__ W,
    short* __restrict__ hIL) {
    __shared__ float Ws[IN_F * HID];
    int t = threadIdx.x;
    for (int i = t; i < IN_F * HID; i += 128) Ws[i] = W[i];
    __syncthreads();
    int nbeg = blockIdx.x * 50;
    for (int n = nbeg; n < nbeg + 50; ++n) {
        float acc = 0.f;
#pragma unroll
        for (int k = 0; k < IN_F; ++k)
            acc += x[(size_t)n * IN_F + k] * Ws[k * HID + t];
        short hh = f2bf(acc);
        hIL[(size_t)n * ROWW + t] = hh;
        hIL[(size_t)n * ROWW + HID + t] = f2bf(acc - bf2f(hh));
    }
}

// -------------------- CSR build --------------------
__global__ __launch_bounds__(256) void hist_kernel(const int* __restrict__ idx, int* __restrict__ count, int n) {
    int e = blockIdx.x * 256 + threadIdx.x;
    if (e < n) atomicAdd(&count[idx[e]], 1);
}

__global__ __launch_bounds__(SB) void scan_part1(
    const int* __restrict__ count, int* __restrict__ bsum, int n) {
    __shared__ int s[SB];
    int t = threadIdx.x;
    int i = blockIdx.x * SB + t;
    s[t] = (i < n) ? count[i] : 0;
    __syncthreads();
    for (int off = SB / 2; off >= 1; off >>= 1) {
        if (t < off) s[t] += s[t + off];
        __syncthreads();
    }
    if (t == 0) bsum[blockIdx.x] = s[0];
}

__global__ __launch_bounds__(256) void scan_part2(
    const int* __restrict__ bsum, int* __restrict__ boff, int nb) {
    __shared__ int s[256];
    int t = threadIdx.x;
    int v0 = (t < nb) ? bsum[t] : 0;
    s[t] = v0;
    __syncthreads();
    for (int off = 1; off < 256; off <<= 1) {
        int v = (t >= off) ? s[t - off] : 0;
        __syncthreads();
        s[t] += v;
        __syncthreads();
    }
    boff[t] = (t == 0) ? 0 : s[t - 1];
}

__global__ __launch_bounds__(SB) void scan_part3(
    const int* __restrict__ count, const int* __restrict__ boff,
    int* __restrict__ ptr, int* __restrict__ cursor, int n) {
    __shared__ int s[SB];
    int b = blockIdx.x, t = threadIdx.x;
    int i = b * SB + t;
    int v = (i < n) ? count[i] : 0;
    s[t] = v;
    __syncthreads();
    for (int off = 1; off < SB; off <<= 1) {
        int u = (t >= off) ? s[t - off] : 0;
        __syncthreads();
        s[t] += u;
        __syncthreads();
    }
    int excl = s[t] - v + boff[b];
    if (i < n) {
        ptr[i] = excl;
        cursor[i] = excl;
        if (i == n - 1) ptr[n] = excl + v;
    }
}

__global__ __launch_bounds__(256) void scatter_kernel(
    const int* __restrict__ src, const int* __restrict__ dst,
    int* __restrict__ cursor, int* __restrict__ sorted_src) {
    int e = blockIdx.x * 256 + threadIdx.x;
    if (e < N_EDGES) {
        int p = atomicAdd(&cursor[dst[e]], 1);
        sorted_src[p] = src[e];
    }
}

// -------------------- aggregate: wave-per-node, single 512B burst per edge ----------
// Row = [H 256B | L 256B]. Lane l reads 8B at row+l*8: lanes 0-31 get H-pairs of
// feats 4l..4l+3, lanes 32-63 get L-pairs of the same feats. Combine via shfl(^32).
__global__ __launch_bounds__(256) void aggregate_kernel(
    const short* __restrict__ hIL,
    const int* __restrict__ row_ptr, const int* __restrict__ sorted_src,
    short* __restrict__ aggIL) {
    int n = (blockIdx.x * 256 + threadIdx.x) >> 6;
    int lane = threadIdx.x & 63;
    const uint2v* __restrict__ R = (const uint2v*)hIL;  // 64 x 8B per row
    int beg = row_ptr[n], end = row_ptr[n + 1];
    float a0 = 0.f, a1 = 0.f, a2 = 0.f, a3 = 0.f;
#define ACC(v) do { \
        union { unsigned u; float f; } u0, u1, u2, u3; \
        u0.u = (v).x << 16; u1.u = (v).x & 0xFFFF0000u; \
        u2.u = (v).y << 16; u3.u = (v).y & 0xFFFF0000u; \
        a0 += u0.f; a1 += u1.f; a2 += u2.f; a3 += u3.f; } while (0)
    int j = beg;
    for (; j + 8 <= end; j += 8) {
        uint2v v[8];
#pragma unroll
        for (int u = 0; u < 8; ++u) {
            int s = __builtin_amdgcn_readfirstlane(sorted_src[j + u]);
            v[u] = R[(size_t)s * 64 + lane];
        }
#pragma unroll
        for (int u = 0; u < 8; ++u) ACC(v[u]);
    }
    for (; j + 2 <= end; j += 2) {
        int s0 = __builtin_amdgcn_readfirstlane(sorted_src[j]);
        int s1 = __builtin_amdgcn_readfirstlane(sorted_src[j + 1]);
        uint2v v0 = R[(size_t)s0 * 64 + lane];
        uint2v v1 = R[(size_t)s1 * 64 + lane];
        ACC(v0); ACC(v1);
    }
    if (j < end) {
        int s = __builtin_amdgcn_readfirstlane(sorted_src[j]);
        uint2v v = R[(size_t)s * 64 + lane];
        ACC(v);
    }
#undef ACC
    // combine H-half and L-half (lane ^ 32 holds the other plane of same feats)
    float t0 = a0 + __shfl(a0, lane ^ 32);
    float t1 = a1 + __shfl(a1, lane ^ 32);
    float t2 = a2 + __shfl(a2, lane ^ 32);
    float t3 = a3 + __shfl(a3, lane ^ 32);
    short h0 = f2bf(t0), h1 = f2bf(t1), h2 = f2bf(t2), h3 = f2bf(t3);
    unsigned w0, w1;
    if (lane < 32) {
        w0 = ((unsigned)(unsigned short)h1 << 16) | (unsigned)(unsigned short)h0;
        w1 = ((unsigned)(unsigned short)h3 << 16) | (unsigned)(unsigned short)h2;
    } else {
        short l0 = f2bf(t0 - bf2f(h0)), l1 = f2bf(t1 - bf2f(h1));
        short l2 = f2bf(t2 - bf2f(h2)), l3 = f2bf(t3 - bf2f(h3));
        w0 = ((unsigned)(unsigned short)l1 << 16) | (unsigned)(unsigned short)l0;
        w1 = ((unsigned)(unsigned short)l3 << 16) | (unsigned)(unsigned short)l2;
    }
    uint2v wv; wv.x = w0; wv.y = w1;
    ((uint2v*)aggIL)[(size_t)n * 64 + lane] = wv;
}

// -------------------- MFMA layer GEMM, LDS-staged epilogue --------------------
__global__ __launch_bounds__(256) void layer_gemm_mfma(
    const short* __restrict__ aggIL, const short* __restrict__ hIL,
    const short* __restrict__ Bp, const float* __restrict__ bias,
    short* __restrict__ outIL,
    const int* __restrict__ bmap, float* __restrict__ pooled, int layer,
    int write_h) {
    __shared__ __align__(16) char smem[34304];
    short* AbBuf = (short*)smem;             // k-loop: [2][4096] shorts
    short* BbBuf = (short*)(smem + 16384);   // k-loop: [2][4096] shorts
    float* Cs    = (float*)smem;             // epilogue: [64][132] fp32 (33792B)
    int*   bmapS = (int*)(smem + 33792);     // 128 ints

    int tid = threadIdx.x;
    int lane = tid & 63;
    int w = tid >> 6;
    int wr = w >> 1, wc = w & 1;
    int m0 = blockIdx.x * BM;

    int i0 = tid, i1 = tid + 256;
    int r0 = i0 >> 2, q0 = i0 & 3;
    int r1 = i1 >> 2, q1 = i1 & 3;

    f32x4 acc[4][4];
#pragma unroll
    for (int m = 0; m < 4; ++m)
#pragma unroll
        for (int n = 0; n < 4; ++n) acc[m][n] = (f32x4)0.f;

    {   // prologue: ks=0 -> term 0 = aggH, kc=0
        short8 a0 = *reinterpret_cast<const short8*>(aggIL + (size_t)(m0 + r0) * ROWW + q0 * 8);
        short8 a1 = *reinterpret_cast<const short8*>(aggIL + (size_t)(m0 + r1) * ROWW + q1 * 8);
        short8 b0 = *reinterpret_cast<const short8*>(Bp + (size_t)i0 * 8);
        short8 b1 = *reinterpret_cast<const short8*>(Bp + (size_t)i1 * 8);
        *reinterpret_cast<short8*>(&AbBuf[(q0 * 128 + r0) * 8]) = a0;
        *reinterpret_cast<short8*>(&AbBuf[(q1 * 128 + r1) * 8]) = a1;
        *reinterpret_cast<short8*>(&BbBuf[i0 * 8]) = b0;
        *reinterpret_cast<short8*>(&BbBuf[i1 * 8]) = b1;
    }
    __syncthreads();

    int kb = lane >> 4;
    int rr = lane & 15;

    for (int ks = 0; ks < KSTEPS; ++ks) {
        int cur = ks & 1;
        short8 a0, a1, b0, b1;
        if (ks < KSTEPS - 1) {
            int nks = ks + 1;
            int term = nks >> 2;
            int kc = (nks & 3) * 32;
            const short* base = (term <= 2) ? aggIL : hIL;
            int poff = (term == 2 || term == 5) ? HID : 0;
            const short* Ap = base + poff + kc;
            a0 = *reinterpret_cast<const short8*>(Ap + (size_t)(m0 + r0) * ROWW + q0 * 8);
            a1 = *reinterpret_cast<const short8*>(Ap + (size_t)(m0 + r1) * ROWW + q1 * 8);
            const short* Bsrc = Bp + (size_t)nks * 4096;
            b0 = *reinterpret_cast<const short8*>(Bsrc + (size_t)i0 * 8);
            b1 = *reinterpret_cast<const short8*>(Bsrc + (size_t)i1 * 8);
        }
        short8 af[4], bfr[4];
#pragma unroll
        for (int m = 0; m < 4; ++m)
            af[m] = *reinterpret_cast<const short8*>(&AbBuf[cur * 4096 + (kb * 128 + wr * 64 + m * 16 + rr) * 8]);
#pragma unroll
        for (int n = 0; n < 4; ++n)
            bfr[n] = *reinterpret_cast<const short8*>(&BbBuf[cur * 4096 + (kb * 128 + wc * 64 + n * 16 + rr) * 8]);
#pragma unroll
        for (int m = 0; m < 4; ++m)
#pragma unroll
            for (int n = 0; n < 4; ++n)
                acc[m][n] = __builtin_amdgcn_mfma_f32_16x16x32_bf16(af[m], bfr[n], acc[m][n], 0, 0, 0);
        if (ks < KSTEPS - 1) {
            int nb = cur ^ 1;
            *reinterpret_cast<short8*>(&AbBuf[nb * 4096 + (q0 * 128 + r0) * 8]) = a0;
            *reinterpret_cast<short8*>(&AbBuf[nb * 4096 + (q1 * 128 + r1) * 8]) = a1;
            *reinterpret_cast<short8*>(&BbBuf[nb * 4096 + i0 * 8]) = b0;
            *reinterpret_cast<short8*>(&BbBuf[nb * 4096 + i1 * 8]) = b1;
        }
        __syncthreads();
    }

    // ---- epilogue: two 64-row chunks through LDS ----
    for (int i = tid; i < 128; i += 256) {
        int gi = m0 + i;
        bmapS[i] = bmap[gi < N_NODES ? gi : N_NODES - 1];
    }
    float bs[4];
    {
        int col = wc * 64 + rr;
#pragma unroll
        for (int n = 0; n < 4; ++n) bs[n] = bias[col + n * 16];
    }
    int colP = tid & 127;     // pooling column
    int half = tid >> 7;      // pooling row-half

    for (int c = 0; c < 2; ++c) {
        if (wr == c) {
            int colb = wc * 64 + rr;
#pragma unroll
            for (int m = 0; m < 4; ++m) {
#pragma unroll
                for (int n = 0; n < 4; ++n) {
#pragma unroll
                    for (int i = 0; i < 4; ++i) {
                        int lr = m * 16 + kb * 4 + i;
                        Cs[lr * 132 + colb + n * 16] = acc[m][n][i] + bs[n];
                    }
                }
            }
        }
        __syncthreads();

        if (write_h) {
#pragma unroll
            for (int p = 0; p < 4; ++p) {
                int idx = p * 256 + tid;
                int lr = idx >> 4;
                int oct = idx & 15;
                const float4* crow = reinterpret_cast<const float4*>(&Cs[lr * 132 + oct * 8]);
                float4 c0 = crow[0], c1 = crow[1];
                float v[8] = {c0.x, c0.y, c0.z, c0.w, c1.x, c1.y, c1.z, c1.w};
                unsigned hw[4], lw[4];
#pragma unroll
                for (int k = 0; k < 4; ++k) {
                    short ha = f2bf(v[2 * k]), hb = f2bf(v[2 * k + 1]);
                    short la = f2bf(v[2 * k] - bf2f(ha)), lb = f2bf(v[2 * k + 1] - bf2f(hb));
                    hw[k] = ((unsigned)(unsigned short)hb << 16) | (unsigned)(unsigned short)ha;
                    lw[k] = ((unsigned)(unsigned short)lb << 16) | (unsigned)(unsigned short)la;
                }
                int row = m0 + c * 64 + lr;
                unsigned* orow = (unsigned*)(outIL + (size_t)row * ROWW);
                uint4v hv; hv.x = hw[0]; hv.y = hw[1]; hv.z = hw[2]; hv.w = hw[3];
                uint4v lv; lv.x = lw[0]; lv.y = lw[1]; lv.z = lw[2]; lv.w = lw[3];
                *reinterpret_cast<uint4v*>(orow + oct * 4) = hv;
                *reinterpret_cast<uint4v*>(orow + (HID / 2) + oct * 4) = lv;
            }
        }

        // pooling: each thread owns one column over 32 rows
        {
            float pacc = 0.f;
            int gprev = -1;
            float* pbase = pooled + (size_t)layer * HID + colP;
            for (int q = 0; q < 32; ++q) {
                int lr = half * 32 + q;
                int grow = m0 + c * 64 + lr;
                if (grow >= N_NODES) break;
                int g = bmapS[c * 64 + lr];
                float v = Cs[lr * 132 + colP];
                if (g != gprev) {
                    if (gprev >= 0) atomicAdd(pbase + (size_t)gprev * (DEPTH * HID), pacc);
                    gprev = g; pacc = v;
                } else {
                    pacc += v;
                }
            }
            if (gprev >= 0) atomicAdd(pbase + (size_t)gprev * (DEPTH * HID), pacc);
        }
        __syncthreads();
    }
}

// -------------------- final: out = pooled @ W_sg + b_sg --------------------
__global__ __launch_bounds__(256) void final_kernel(
    const float* __restrict__ pooled, const float* __restrict__ Wsg,
    const float* __restrict__ bsg, float* __restrict__ out) {
    int t = threadIdx.x & 31;
    int g = blockIdx.x * 8 + (threadIdx.x >> 5);
    float acc = bsg[t];
    const float* prow = pooled + (size_t)g * (DEPTH * HID);
    for (int k = 0; k < DEPTH * HID; ++k)
        acc += prow[k] * Wsg[k * IN_F + t];
    out[g * IN_F + t] = acc;
}

extern "C" void kernel_launch(void* const* d_in, const int* in_sizes, int n_in,
                              void* d_out, int out_size, void* d_ws, size_t ws_size,
                              hipStream_t stream) {
    const float* x       = (const float*)d_in[0];
    const int*   edge    = (const int*)d_in[1];
    const int*   bmap    = (const int*)d_in[2];
    // d_in[3] = num_graphs (512); d_in[8]/d_in[9] = W_ws/b_ws dead (softmax over dim-1 == 1)
    const float* W_embed = (const float*)d_in[4];
    const float* W_rel   = (const float*)d_in[5];
    const float* b_rel   = (const float*)d_in[6];
    const float* W_root  = (const float*)d_in[7];
    const float* W_sg    = (const float*)d_in[10];
    const float* b_sg    = (const float*)d_in[11];
    float* out = (float*)d_out;

    const int* src = edge;
    const int* dst = edge + N_EDGES;

    char* ws = (char*)d_ws;
    auto alloc = [&](size_t bytes) -> char* {
        char* p = ws;
        ws += (bytes + 255) & ~(size_t)255;
        return p;
    };
    const size_t rowB = (size_t)PADN * ROWW * 2;  // interleaved [H|L] buffer
    short* h_a   = (short*)alloc(rowB);
    short* h_b   = (short*)alloc(rowB);
    short* aggIL = (short*)alloc(rowB);
    float* pooled = (float*)alloc((size_t)N_GRAPHS * DEPTH * HID * 4);
    int* counts     = (int*)alloc((size_t)N_NODES * 4);
    int* row_ptr    = (int*)alloc((size_t)(N_NODES + 1) * 4);
    int* cursor     = (int*)alloc((size_t)N_NODES * 4);
    int* sorted_src = (int*)alloc((size_t)N_EDGES * 4);
    int* bsum       = (int*)alloc((size_t)256 * 4);
    int* boff       = (int*)alloc((size_t)256 * 4);
    short* Bpacked  = (short*)alloc((size_t)PACK_CHUNKS * 8 * 2);

    hipMemsetAsync(counts, 0, (size_t)N_NODES * 4, stream);
    hipMemsetAsync(pooled, 0, (size_t)N_GRAPHS * DEPTH * HID * 4, stream);

    pack_weights<<<(PACK_CHUNKS + 255) / 256, 256, 0, stream>>>(W_rel, W_root, Bpacked);
    embed_kernel<<<1000, 128, 0, stream>>>(x, W_embed, h_a);

    hist_kernel<<<(N_EDGES + 255) / 256, 256, 0, stream>>>(dst, counts, N_EDGES);
    scan_part1<<<NSB, SB, 0, stream>>>(counts, bsum, N_NODES);
    scan_part2<<<1, 256, 0, stream>>>(bsum, boff, NSB);
    scan_part3<<<NSB, SB, 0, stream>>>(counts, boff, row_ptr, cursor, N_NODES);
    scatter_kernel<<<(N_EDGES + 255) / 256, 256, 0, stream>>>(src, dst, cursor, sorted_src);

    short *hc = h_a, *hn = h_b;
    for (int i = 0; i < DEPTH; ++i) {
        aggregate_kernel<<<(N_NODES + 3) / 4, 256, 0, stream>>>(hc, row_ptr, sorted_src, aggIL);
        layer_gemm_mfma<<<GBLK, 256, 0, stream>>>(aggIL, hc,
                                                  Bpacked + (size_t)i * KSTEPS * 4096,
                                                  b_rel + (size_t)i * HID,
                                                  hn, bmap, pooled, i,
                                                  (i < DEPTH - 1) ? 1 : 0);
        short* t = hc; hc = hn; hn = t;
    }

    final_kernel<<<N_GRAPHS / 8, 256, 0, stream>>>(pooled, W_sg, b_sg, out);
}